// Round 1
// baseline (707.446 us; speedup 1.0000x reference)
//
#include <hip/hip_runtime.h>

#define D 128
#define TPAD 132
#define NPB 256          // nodes per bucket (dst >> 8)
#define KMAX 512         // max buckets (n <= 131072)
#define CHUNK 4096       // edges per block in bucket passes

// ---------------- CSR build ----------------
// No per-node global atomics anywhere: bucket histogram is LDS-aggregated over
// 512 counters; per-node counts/offsets are derived per-bucket in LDS.

__global__ __launch_bounds__(256) void zero_int(int* __restrict__ p, int n) {
    int i = blockIdx.x * 256 + threadIdx.x;
    if (i < n) p[i] = 0;
}

__global__ __launch_bounds__(256) void bucket_hist_kernel(const int* __restrict__ dst,
                                                          int* __restrict__ bucket_cnt, int E) {
    __shared__ int scnt[KMAX];
    int t = threadIdx.x;
    for (int i = t; i < KMAX; i += 256) scnt[i] = 0;
    __syncthreads();
    int base = blockIdx.x * CHUNK;
    int nE = min(CHUNK, E - base);
    for (int i = t; i < nE; i += 256)
        atomicAdd(&scnt[dst[base + i] >> 8], 1);
    __syncthreads();
    for (int i = t; i < KMAX; i += 256)
        if (scnt[i]) atomicAdd(&bucket_cnt[i], scnt[i]);
}

// Exclusive scan of bucket_cnt[K] -> bucket_ptr[K+1], bucket_cur[K]=bucket_ptr[K]
__global__ __launch_bounds__(KMAX) void bucket_scan_kernel(const int* __restrict__ bucket_cnt,
                                                           int* __restrict__ bucket_ptr,
                                                           int* __restrict__ bucket_cur,
                                                           int K, int E) {
    __shared__ int sh[KMAX];
    int t = threadIdx.x;
    int v = (t < K) ? bucket_cnt[t] : 0;
    sh[t] = v;
    __syncthreads();
    for (int off = 1; off < KMAX; off <<= 1) {
        int add = (t >= off) ? sh[t - off] : 0;
        __syncthreads();
        sh[t] += add;
        __syncthreads();
    }
    if (t < K) {
        int ex = sh[t] - v;
        bucket_ptr[t] = ex;
        bucket_cur[t] = ex;
    }
    if (t == 0) bucket_ptr[K] = E;
}

// Phase A: partition edges into dst-buckets. Writes are contiguous runs per
// (block,bucket) -> near-full-line writebacks instead of 64B per 4B store.
__global__ __launch_bounds__(256) void bucket_scatter_kernel(const int* __restrict__ src,
                                                             const int* __restrict__ dst,
                                                             int* __restrict__ bucket_cur,
                                                             int2* __restrict__ bdata, int E) {
    __shared__ int sdst[CHUNK];     // 16 KB
    __shared__ int scnt[KMAX];      // 2 KB (counts, then local cursors)
    __shared__ int sbase[KMAX];     // 2 KB
    int t = threadIdx.x;
    int base = blockIdx.x * CHUNK;
    int nE = min(CHUNK, E - base);
    for (int i = t; i < KMAX; i += 256) scnt[i] = 0;
    __syncthreads();
    for (int i = t; i < nE; i += 256) {
        int d = dst[base + i];
        sdst[i] = d;
        atomicAdd(&scnt[d >> 8], 1);
    }
    __syncthreads();
    for (int i = t; i < KMAX; i += 256) {
        int c = scnt[i];
        sbase[i] = c ? atomicAdd(&bucket_cur[i], c) : 0;
        scnt[i] = 0;                // reuse as local cursor
    }
    __syncthreads();
    for (int i = t; i < nE; i += 256) {
        int d = sdst[i];
        int b = d >> 8;
        int pos = sbase[b] + atomicAdd(&scnt[b], 1);
        bdata[pos] = make_int2(src[base + i], d);
    }
}

// Per-bucket: LDS histogram of dst -> per-node count; LDS exclusive scan gives
// row_ptr[node] = bucket_ptr[b] + scan (buckets are contiguous dst ranges, so
// this IS the global CSR offset — no global scan chain needed). Also emits dis.
__global__ __launch_bounds__(256) void csr_count_scan_kernel(const int2* __restrict__ bdata,
                                                             const int* __restrict__ bucket_ptr,
                                                             int* __restrict__ row_ptr,
                                                             float* __restrict__ dis,
                                                             int n, int E, int K) {
    __shared__ int scnt[NPB];
    __shared__ int sh[NPB];
    int b = blockIdx.x;
    int node0 = b << 8;
    int nn = min(NPB, n - node0);
    int t = threadIdx.x;
    scnt[t] = 0;
    __syncthreads();
    int p0 = bucket_ptr[b], p1 = bucket_ptr[b + 1];
    for (int i = p0 + t; i < p1; i += 256)
        atomicAdd(&scnt[bdata[i].y - node0], 1);
    __syncthreads();
    int v = scnt[t];
    sh[t] = v;
    __syncthreads();
    for (int off = 1; off < NPB; off <<= 1) {
        int add = (t >= off) ? sh[t - off] : 0;
        __syncthreads();
        sh[t] += add;
        __syncthreads();
    }
    if (t < nn) {
        row_ptr[node0 + t] = p0 + sh[t] - v;     // exclusive
        dis[node0 + t] = rsqrtf((float)(v + 1)); // +1 self-loop
    }
    if (b == K - 1 && t == 0) row_ptr[n] = E;
}

// Phase B: one block per bucket owns a contiguous csr_src region exclusively;
// per-node cursors live in LDS (no global atomics, no cross-XCD ping-pong).
__global__ __launch_bounds__(256) void csr_fill_kernel(const int2* __restrict__ bdata,
                                                       const int* __restrict__ bucket_ptr,
                                                       const int* __restrict__ row_ptr,
                                                       int* __restrict__ csr_src, int n) {
    __shared__ int cursor[NPB];
    int b = blockIdx.x;
    int node0 = b << 8;
    int nn = min(NPB, n - node0);
    int t = threadIdx.x;
    if (t < nn) cursor[t] = row_ptr[node0 + t];
    __syncthreads();
    int p0 = bucket_ptr[b], p1 = bucket_ptr[b + 1];
    for (int i = p0 + t; i < p1; i += 256) {
        int2 e = bdata[i];
        int pos = atomicAdd(&cursor[e.y - node0], 1);
        csr_src[pos] = e.x;
    }
}

// ---------------- GEMM: C[n x 128] = dis[row] * ((relu?)A[n x 128] @ W[128 x 128]) ----
// Structure (R6): full A-tile staged in LDS ONCE (k-major, 66 KB, one barrier),
// W streamed from global (64 KB, L2-resident) with register double-buffering of
// 4-k groups. FMA-issue bound: 8192 FMA/thread * 2cyc = 16384 cyc/wave.
// A-frag LDS reads are 16-lane broadcasts (conflict-free).
// __launch_bounds__(256,2): VGPR cap 256 (~150 used, no spill); 2 blocks/CU is
// the LDS limit anyway.

template <bool RELU>
__global__ __launch_bounds__(256, 2) void gemm_kernel(const float* __restrict__ A,
                                                      const float* __restrict__ W,
                                                      const float* __restrict__ dis,
                                                      float* __restrict__ C, int n) {
    __shared__ float sAT[128 * TPAD];   // [k][r], 66 KB
    int tid = threadIdx.x;
    int base = blockIdx.x * 128;
    int tx = tid & 15, ty = tid >> 4;

    // ---- stage A (k-major transpose), one pass ----
    const float4* A4 = (const float4*)A;     // row stride = 32 float4
#pragma unroll
    for (int it = 0; it < 16; ++it) {
        int idx = it * 256 + tid;            // float4 index 0..4095
        int r = idx >> 5, kq = idx & 31;     // row in tile, float4-within-row
        int grow = base + r;
        float4 va = (grow < n) ? A4[(size_t)grow * 32 + kq]
                               : make_float4(0.f, 0.f, 0.f, 0.f);
        if (RELU) {
            va.x = fmaxf(va.x, 0.f); va.y = fmaxf(va.y, 0.f);
            va.z = fmaxf(va.z, 0.f); va.w = fmaxf(va.w, 0.f);
        }
        int k0 = kq * 4;
        sAT[(k0 + 0) * TPAD + r] = va.x;
        sAT[(k0 + 1) * TPAD + r] = va.y;
        sAT[(k0 + 2) * TPAD + r] = va.z;
        sAT[(k0 + 3) * TPAD + r] = va.w;
    }
    __syncthreads();

    float acc[8][8];
#pragma unroll
    for (int i = 0; i < 8; ++i)
#pragma unroll
        for (int j = 0; j < 8; ++j) acc[i][j] = 0.f;

    const float4* W4 = (const float4*)W;     // row stride = 32 float4
    float4 wA[8], wB[8];                     // 4-k groups: w[2*kk], w[2*kk+1]

    // prologue: group k=0..3
#pragma unroll
    for (int kk = 0; kk < 4; ++kk) {
        wA[2 * kk + 0] = W4[(size_t)kk * 32 + tx * 2 + 0];
        wA[2 * kk + 1] = W4[(size_t)kk * 32 + tx * 2 + 1];
    }

#define COMPUTE4(kb, wbuf)                                                     \
    {                                                                          \
        _Pragma("unroll")                                                      \
        for (int kk = 0; kk < 4; ++kk) {                                       \
            int k = (kb) + kk;                                                 \
            float4 a0 = *(const float4*)&sAT[k * TPAD + ty * 8];               \
            float4 a1 = *(const float4*)&sAT[k * TPAD + ty * 8 + 4];           \
            float a[8] = {a0.x, a0.y, a0.z, a0.w, a1.x, a1.y, a1.z, a1.w};     \
            float4 w0 = wbuf[2 * kk + 0], w1 = wbuf[2 * kk + 1];               \
            float w[8] = {w0.x, w0.y, w0.z, w0.w, w1.x, w1.y, w1.z, w1.w};     \
            _Pragma("unroll")                                                  \
            for (int i = 0; i < 8; ++i)                                        \
                _Pragma("unroll")                                              \
                for (int j = 0; j < 8; ++j)                                    \
                    acc[i][j] = fmaf(a[i], w[j], acc[i][j]);                   \
        }                                                                      \
    }

    for (int kb = 0; kb < 128; kb += 8) {
        // prefetch group kb+4 into wB (always valid: kb+4 <= 124)
#pragma unroll
        for (int kk = 0; kk < 4; ++kk) {
            wB[2 * kk + 0] = W4[(size_t)(kb + 4 + kk) * 32 + tx * 2 + 0];
            wB[2 * kk + 1] = W4[(size_t)(kb + 4 + kk) * 32 + tx * 2 + 1];
        }
        COMPUTE4(kb, wA);
        if (kb + 8 < 128) {
            // prefetch group kb+8 into wA
#pragma unroll
            for (int kk = 0; kk < 4; ++kk) {
                wA[2 * kk + 0] = W4[(size_t)(kb + 8 + kk) * 32 + tx * 2 + 0];
                wA[2 * kk + 1] = W4[(size_t)(kb + 8 + kk) * 32 + tx * 2 + 1];
            }
        }
        COMPUTE4(kb + 4, wB);
    }
#undef COMPUTE4

#pragma unroll
    for (int i = 0; i < 8; ++i) {
        int row = base + ty * 8 + i;
        if (row < n) {
            float di = dis[row];
            float4 o0 = make_float4(acc[i][0] * di, acc[i][1] * di,
                                    acc[i][2] * di, acc[i][3] * di);
            float4 o1 = make_float4(acc[i][4] * di, acc[i][5] * di,
                                    acc[i][6] * di, acc[i][7] * di);
            *(float4*)&C[row * D + tx * 8] = o0;
            *(float4*)&C[row * D + tx * 8 + 4] = o1;
        }
    }
}

// ---------------- Aggregation: out[i] = dis_i*(H'[i] + sum_e H'[src_e]) + b ----------
// R7: wave split into two 32-lane halves; each half reads a FULL 512 B row as
// float4 (32 lanes x 16 B), so one VMEM instruction gathers TWO edges = 1 KB
// (2x bytes per vmcnt slot vs the float2/64-lane scheme). Batch of 8
// instructions = 16 edges (8 KB) in flight per wave, with next-batch index
// prefetch. Tail is wave-uniform 8/4/2/1-edge steps (keeps >=4 independent
// gathers in flight for low-degree nodes instead of a latency-chained tail).
// Cross-half combine: 4x shfl_xor(32).

__global__ __launch_bounds__(256) void aggregate_kernel(const float* __restrict__ Hs,
                                                        const int* __restrict__ row_ptr,
                                                        const int* __restrict__ csr_src,
                                                        const float* __restrict__ dis,
                                                        const float* __restrict__ b,
                                                        float* __restrict__ out, int n) {
    int node = blockIdx.x * 4 + (threadIdx.x >> 6);
    if (node >= n) return;
    int lane = threadIdx.x & 63;
    int h = lane >> 5;          // which half-wave (edge parity)
    int sl = lane & 31;         // sublane within half: float4 slot in the row
    const float4* __restrict__ H4 = (const float4*)Hs;

    float4 acc = make_float4(0.f, 0.f, 0.f, 0.f);
    if (h == 0) {               // self-loop term, counted once (half 0)
        float4 s = H4[(size_t)node * 32 + sl];
        acc.x = s.x; acc.y = s.y; acc.z = s.z; acc.w = s.w;
    }

    int p0 = row_ptr[node], p1 = row_ptr[node + 1];
    int p = p0;
    int nb = (p1 - p0) >> 4;    // batches of 16 edges (8 gather instrs)
    if (nb > 0) {
        int idx[8];
#pragma unroll
        for (int u = 0; u < 8; ++u) idx[u] = csr_src[p + 2 * u + h];
        for (int bb = 1; bb < nb; ++bb) {
            int nxt[8];
#pragma unroll
            for (int u = 0; u < 8; ++u) nxt[u] = csr_src[p + 16 + 2 * u + h];
            float4 v[8];
#pragma unroll
            for (int u = 0; u < 8; ++u) v[u] = H4[(size_t)idx[u] * 32 + sl];
#pragma unroll
            for (int u = 0; u < 8; ++u) {
                acc.x += v[u].x; acc.y += v[u].y; acc.z += v[u].z; acc.w += v[u].w;
            }
#pragma unroll
            for (int u = 0; u < 8; ++u) idx[u] = nxt[u];
            p += 16;
        }
        {
            float4 v[8];
#pragma unroll
            for (int u = 0; u < 8; ++u) v[u] = H4[(size_t)idx[u] * 32 + sl];
#pragma unroll
            for (int u = 0; u < 8; ++u) {
                acc.x += v[u].x; acc.y += v[u].y; acc.z += v[u].z; acc.w += v[u].w;
            }
            p += 16;
        }
    }
    // tail: rem in [0,15], wave-uniform branches
    if (p + 8 <= p1) {          // 8 edges, 4 instrs
        int idx[4]; float4 v[4];
#pragma unroll
        for (int u = 0; u < 4; ++u) idx[u] = csr_src[p + 2 * u + h];
#pragma unroll
        for (int u = 0; u < 4; ++u) v[u] = H4[(size_t)idx[u] * 32 + sl];
#pragma unroll
        for (int u = 0; u < 4; ++u) {
            acc.x += v[u].x; acc.y += v[u].y; acc.z += v[u].z; acc.w += v[u].w;
        }
        p += 8;
    }
    if (p + 4 <= p1) {          // 4 edges, 2 instrs
        int i0 = csr_src[p + h];
        int i1 = csr_src[p + 2 + h];
        float4 v0 = H4[(size_t)i0 * 32 + sl];
        float4 v1 = H4[(size_t)i1 * 32 + sl];
        acc.x += v0.x + v1.x; acc.y += v0.y + v1.y;
        acc.z += v0.z + v1.z; acc.w += v0.w + v1.w;
        p += 4;
    }
    if (p + 2 <= p1) {          // 2 edges, 1 instr
        int i0 = csr_src[p + h];
        float4 v0 = H4[(size_t)i0 * 32 + sl];
        acc.x += v0.x; acc.y += v0.y; acc.z += v0.z; acc.w += v0.w;
        p += 2;
    }
    if (p < p1 && h == 0) {     // odd edge, half 0 only
        int i0 = csr_src[p];
        float4 v0 = H4[(size_t)i0 * 32 + sl];
        acc.x += v0.x; acc.y += v0.y; acc.z += v0.z; acc.w += v0.w;
    }

    // cross-half combine: lane <-> lane^32
    acc.x += __shfl_xor(acc.x, 32);
    acc.y += __shfl_xor(acc.y, 32);
    acc.z += __shfl_xor(acc.z, 32);
    acc.w += __shfl_xor(acc.w, 32);

    if (h == 0) {
        float di = dis[node];
        float4 b4 = *(const float4*)(b + sl * 4);
        float4 o;
        o.x = fmaf(acc.x, di, b4.x);
        o.y = fmaf(acc.y, di, b4.y);
        o.z = fmaf(acc.z, di, b4.z);
        o.w = fmaf(acc.w, di, b4.w);
        ((float4*)(out + (size_t)node * D))[sl] = o;
    }
}

// ---------------- launch ----------------

extern "C" void kernel_launch(void* const* d_in, const int* in_sizes, int n_in,
                              void* d_out, int out_size, void* d_ws, size_t ws_size,
                              hipStream_t stream) {
    const float* x  = (const float*)d_in[0];
    const int*   ei = (const int*)d_in[1];
    const float* W1 = (const float*)d_in[2];
    const float* b1 = (const float*)d_in[3];
    const float* W2 = (const float*)d_in[4];
    const float* b2 = (const float*)d_in[5];
    const float* W3 = (const float*)d_in[6];
    const float* b3 = (const float*)d_in[7];
    float* out = (float*)d_out;

    int n = in_sizes[0] / D;
    int E = in_sizes[1] / 2;
    const int* src = ei;
    const int* dst = ei + E;
    int K = (n + NPB - 1) >> 8;     // buckets

    char* ws = (char*)d_ws;
    float* bufA      = (float*)ws; ws += (size_t)n * D * sizeof(float);
    float* dis       = (float*)ws; ws += (size_t)n * sizeof(float);
    int* row_ptr     = (int*)ws;   ws += (size_t)(n + 1) * sizeof(int);
    int* csr_src     = (int*)ws;   ws += (size_t)E * sizeof(int);
    int* bucket_cnt  = (int*)ws;   ws += KMAX * sizeof(int);
    int* bucket_ptr  = (int*)ws;   ws += (KMAX + 1) * sizeof(int);
    int* bucket_cur  = (int*)ws;   ws += KMAX * sizeof(int);
    int2* bdata      = (int2*)bufA;   // aliases bufA; dead before first GEMM writes it

    int gC = (E + CHUNK - 1) / CHUNK; // 391
    int gM = (n + 127) / 128;         // 782
    int gA = (n + 3) / 4;             // 25000

    // CSR build — no per-node global atomics anywhere.
    zero_int<<<2, 256, 0, stream>>>(bucket_cnt, KMAX);
    bucket_hist_kernel<<<gC, 256, 0, stream>>>(dst, bucket_cnt, E);
    bucket_scan_kernel<<<1, KMAX, 0, stream>>>(bucket_cnt, bucket_ptr, bucket_cur, K, E);
    bucket_scatter_kernel<<<gC, 256, 0, stream>>>(src, dst, bucket_cur, bdata, E);
    csr_count_scan_kernel<<<K, 256, 0, stream>>>(bdata, bucket_ptr, row_ptr, dis, n, E, K);
    csr_fill_kernel<<<K, 256, 0, stream>>>(bdata, bucket_ptr, row_ptr, csr_src, n);

    // Layer 1: H' = dis*(x@W1) -> bufA ; agg+b1 -> out
    gemm_kernel<false><<<gM, 256, 0, stream>>>(x, W1, dis, bufA, n);
    aggregate_kernel<<<gA, 256, 0, stream>>>(bufA, row_ptr, csr_src, dis, b1, out, n);
    // Layer 2: H' = dis*(relu(out)@W2) -> bufA ; agg+b2 -> out
    gemm_kernel<true><<<gM, 256, 0, stream>>>(out, W2, dis, bufA, n);
    aggregate_kernel<<<gA, 256, 0, stream>>>(bufA, row_ptr, csr_src, dis, b2, out, n);
    // Layer 3: H' = dis*(relu(out)@W3) -> bufA ; agg+b3 -> out
    gemm_kernel<true><<<gM, 256, 0, stream>>>(out, W3, dis, bufA, n);
    aggregate_kernel<<<gA, 256, 0, stream>>>(bufA, row_ptr, csr_src, dis, b3, out, n);
}

// Round 2
// 547.693 us; speedup vs baseline: 1.2917x; 1.2917x over previous
//
#include <hip/hip_runtime.h>
#include <hip/hip_fp16.h>

#define D 128
#define TPAD 132
#define NPB 256          // nodes per bucket (dst >> 8)
#define KMAX 512         // max buckets (n <= 131072)
#define CHUNK 4096       // edges per block in bucket passes

// ---------------- CSR build ----------------
// No per-node global atomics anywhere: bucket histogram is LDS-aggregated over
// 512 counters; per-node counts/offsets are derived per-bucket in LDS.

__global__ __launch_bounds__(256) void zero_int(int* __restrict__ p, int n) {
    int i = blockIdx.x * 256 + threadIdx.x;
    if (i < n) p[i] = 0;
}

__global__ __launch_bounds__(256) void bucket_hist_kernel(const int* __restrict__ dst,
                                                          int* __restrict__ bucket_cnt, int E) {
    __shared__ int scnt[KMAX];
    int t = threadIdx.x;
    for (int i = t; i < KMAX; i += 256) scnt[i] = 0;
    __syncthreads();
    int base = blockIdx.x * CHUNK;
    int nE = min(CHUNK, E - base);
    for (int i = t; i < nE; i += 256)
        atomicAdd(&scnt[dst[base + i] >> 8], 1);
    __syncthreads();
    for (int i = t; i < KMAX; i += 256)
        if (scnt[i]) atomicAdd(&bucket_cnt[i], scnt[i]);
}

// Exclusive scan of bucket_cnt[K] -> bucket_ptr[K+1], bucket_cur[K]=bucket_ptr[K]
__global__ __launch_bounds__(KMAX) void bucket_scan_kernel(const int* __restrict__ bucket_cnt,
                                                           int* __restrict__ bucket_ptr,
                                                           int* __restrict__ bucket_cur,
                                                           int K, int E) {
    __shared__ int sh[KMAX];
    int t = threadIdx.x;
    int v = (t < K) ? bucket_cnt[t] : 0;
    sh[t] = v;
    __syncthreads();
    for (int off = 1; off < KMAX; off <<= 1) {
        int add = (t >= off) ? sh[t - off] : 0;
        __syncthreads();
        sh[t] += add;
        __syncthreads();
    }
    if (t < K) {
        int ex = sh[t] - v;
        bucket_ptr[t] = ex;
        bucket_cur[t] = ex;
    }
    if (t == 0) bucket_ptr[K] = E;
}

// Phase A: partition edges into dst-buckets. Writes are contiguous runs per
// (block,bucket) -> near-full-line writebacks instead of 64B per 4B store.
__global__ __launch_bounds__(256) void bucket_scatter_kernel(const int* __restrict__ src,
                                                             const int* __restrict__ dst,
                                                             int* __restrict__ bucket_cur,
                                                             int2* __restrict__ bdata, int E) {
    __shared__ int sdst[CHUNK];     // 16 KB
    __shared__ int scnt[KMAX];      // 2 KB (counts, then local cursors)
    __shared__ int sbase[KMAX];     // 2 KB
    int t = threadIdx.x;
    int base = blockIdx.x * CHUNK;
    int nE = min(CHUNK, E - base);
    for (int i = t; i < KMAX; i += 256) scnt[i] = 0;
    __syncthreads();
    for (int i = t; i < nE; i += 256) {
        int d = dst[base + i];
        sdst[i] = d;
        atomicAdd(&scnt[d >> 8], 1);
    }
    __syncthreads();
    for (int i = t; i < KMAX; i += 256) {
        int c = scnt[i];
        sbase[i] = c ? atomicAdd(&bucket_cur[i], c) : 0;
        scnt[i] = 0;                // reuse as local cursor
    }
    __syncthreads();
    for (int i = t; i < nE; i += 256) {
        int d = sdst[i];
        int b = d >> 8;
        int pos = sbase[b] + atomicAdd(&scnt[b], 1);
        bdata[pos] = make_int2(src[base + i], d);
    }
}

// Per-bucket: LDS histogram of dst -> per-node count; LDS exclusive scan gives
// row_ptr[node] = bucket_ptr[b] + scan (buckets are contiguous dst ranges, so
// this IS the global CSR offset — no global scan chain needed). Also emits dis.
__global__ __launch_bounds__(256) void csr_count_scan_kernel(const int2* __restrict__ bdata,
                                                             const int* __restrict__ bucket_ptr,
                                                             int* __restrict__ row_ptr,
                                                             float* __restrict__ dis,
                                                             int n, int E, int K) {
    __shared__ int scnt[NPB];
    __shared__ int sh[NPB];
    int b = blockIdx.x;
    int node0 = b << 8;
    int nn = min(NPB, n - node0);
    int t = threadIdx.x;
    scnt[t] = 0;
    __syncthreads();
    int p0 = bucket_ptr[b], p1 = bucket_ptr[b + 1];
    for (int i = p0 + t; i < p1; i += 256)
        atomicAdd(&scnt[bdata[i].y - node0], 1);
    __syncthreads();
    int v = scnt[t];
    sh[t] = v;
    __syncthreads();
    for (int off = 1; off < NPB; off <<= 1) {
        int add = (t >= off) ? sh[t - off] : 0;
        __syncthreads();
        sh[t] += add;
        __syncthreads();
    }
    if (t < nn) {
        row_ptr[node0 + t] = p0 + sh[t] - v;     // exclusive
        dis[node0 + t] = rsqrtf((float)(v + 1)); // +1 self-loop
    }
    if (b == K - 1 && t == 0) row_ptr[n] = E;
}

// Phase B: one block per bucket owns a contiguous csr_src region exclusively;
// per-node cursors live in LDS (no global atomics, no cross-XCD ping-pong).
__global__ __launch_bounds__(256) void csr_fill_kernel(const int2* __restrict__ bdata,
                                                       const int* __restrict__ bucket_ptr,
                                                       const int* __restrict__ row_ptr,
                                                       int* __restrict__ csr_src, int n) {
    __shared__ int cursor[NPB];
    int b = blockIdx.x;
    int node0 = b << 8;
    int nn = min(NPB, n - node0);
    int t = threadIdx.x;
    if (t < nn) cursor[t] = row_ptr[node0 + t];
    __syncthreads();
    int p0 = bucket_ptr[b], p1 = bucket_ptr[b + 1];
    for (int i = p0 + t; i < p1; i += 256) {
        int2 e = bdata[i];
        int pos = atomicAdd(&cursor[e.y - node0], 1);
        csr_src[pos] = e.x;
    }
}

// ---------------- GEMM: C[n x 128] = fp16( dis[row] * ((relu?)A @ W) ) ----------
// R8: epilogue converts to fp16 (RTN) — H' is an internal intermediate consumed
// only by the gather; halving its row size (512B -> 256B) halves the
// beyond-L2 traffic of the bandwidth-ceiling-bound aggregate.
// Compute path unchanged from R6 (fp32 FMA-issue bound).

template <bool RELU>
__global__ __launch_bounds__(256, 2) void gemm_kernel(const float* __restrict__ A,
                                                      const float* __restrict__ W,
                                                      const float* __restrict__ dis,
                                                      __half* __restrict__ C, int n) {
    __shared__ float sAT[128 * TPAD];   // [k][r], 66 KB
    int tid = threadIdx.x;
    int base = blockIdx.x * 128;
    int tx = tid & 15, ty = tid >> 4;

    // ---- stage A (k-major transpose), one pass ----
    const float4* A4 = (const float4*)A;     // row stride = 32 float4
#pragma unroll
    for (int it = 0; it < 16; ++it) {
        int idx = it * 256 + tid;            // float4 index 0..4095
        int r = idx >> 5, kq = idx & 31;     // row in tile, float4-within-row
        int grow = base + r;
        float4 va = (grow < n) ? A4[(size_t)grow * 32 + kq]
                               : make_float4(0.f, 0.f, 0.f, 0.f);
        if (RELU) {
            va.x = fmaxf(va.x, 0.f); va.y = fmaxf(va.y, 0.f);
            va.z = fmaxf(va.z, 0.f); va.w = fmaxf(va.w, 0.f);
        }
        int k0 = kq * 4;
        sAT[(k0 + 0) * TPAD + r] = va.x;
        sAT[(k0 + 1) * TPAD + r] = va.y;
        sAT[(k0 + 2) * TPAD + r] = va.z;
        sAT[(k0 + 3) * TPAD + r] = va.w;
    }
    __syncthreads();

    float acc[8][8];
#pragma unroll
    for (int i = 0; i < 8; ++i)
#pragma unroll
        for (int j = 0; j < 8; ++j) acc[i][j] = 0.f;

    const float4* W4 = (const float4*)W;     // row stride = 32 float4
    float4 wA[8], wB[8];                     // 4-k groups: w[2*kk], w[2*kk+1]

    // prologue: group k=0..3
#pragma unroll
    for (int kk = 0; kk < 4; ++kk) {
        wA[2 * kk + 0] = W4[(size_t)kk * 32 + tx * 2 + 0];
        wA[2 * kk + 1] = W4[(size_t)kk * 32 + tx * 2 + 1];
    }

#define COMPUTE4(kb, wbuf)                                                     \
    {                                                                          \
        _Pragma("unroll")                                                      \
        for (int kk = 0; kk < 4; ++kk) {                                       \
            int k = (kb) + kk;                                                 \
            float4 a0 = *(const float4*)&sAT[k * TPAD + ty * 8];               \
            float4 a1 = *(const float4*)&sAT[k * TPAD + ty * 8 + 4];           \
            float a[8] = {a0.x, a0.y, a0.z, a0.w, a1.x, a1.y, a1.z, a1.w};     \
            float4 w0 = wbuf[2 * kk + 0], w1 = wbuf[2 * kk + 1];               \
            float w[8] = {w0.x, w0.y, w0.z, w0.w, w1.x, w1.y, w1.z, w1.w};     \
            _Pragma("unroll")                                                  \
            for (int i = 0; i < 8; ++i)                                        \
                _Pragma("unroll")                                              \
                for (int j = 0; j < 8; ++j)                                    \
                    acc[i][j] = fmaf(a[i], w[j], acc[i][j]);                   \
        }                                                                      \
    }

    for (int kb = 0; kb < 128; kb += 8) {
        // prefetch group kb+4 into wB (always valid: kb+4 <= 124)
#pragma unroll
        for (int kk = 0; kk < 4; ++kk) {
            wB[2 * kk + 0] = W4[(size_t)(kb + 4 + kk) * 32 + tx * 2 + 0];
            wB[2 * kk + 1] = W4[(size_t)(kb + 4 + kk) * 32 + tx * 2 + 1];
        }
        COMPUTE4(kb, wA);
        if (kb + 8 < 128) {
            // prefetch group kb+8 into wA
#pragma unroll
            for (int kk = 0; kk < 4; ++kk) {
                wA[2 * kk + 0] = W4[(size_t)(kb + 8 + kk) * 32 + tx * 2 + 0];
                wA[2 * kk + 1] = W4[(size_t)(kb + 8 + kk) * 32 + tx * 2 + 1];
            }
        }
        COMPUTE4(kb + 4, wB);
    }
#undef COMPUTE4

#pragma unroll
    for (int i = 0; i < 8; ++i) {
        int row = base + ty * 8 + i;
        if (row < n) {
            float di = dis[row];
            union { __half2 h2[4]; float4 f4; } cvt;
            cvt.h2[0] = __floats2half2_rn(acc[i][0] * di, acc[i][1] * di);
            cvt.h2[1] = __floats2half2_rn(acc[i][2] * di, acc[i][3] * di);
            cvt.h2[2] = __floats2half2_rn(acc[i][4] * di, acc[i][5] * di);
            cvt.h2[3] = __floats2half2_rn(acc[i][6] * di, acc[i][7] * di);
            *(float4*)&C[(size_t)row * D + tx * 8] = cvt.f4;   // 8 halves = 16B
        }
    }
}

// ---------------- Aggregation: out[i] = dis_i*(H'[i] + sum_e H'[src_e]) + b ----------
// R8: H' is fp16 — row = 256B, one half2 per lane, one VMEM instruction per
// edge (64 lanes x 4B). fp32 accumulation. Batch-8 gather pipeline with
// next-batch index prefetch (R6 shape; MLP shape is irrelevant at the
// beyond-L2 bandwidth ceiling, so keep the low-VGPR variant).

__global__ __launch_bounds__(256) void aggregate_kernel(const __half2* __restrict__ Hs,
                                                        const int* __restrict__ row_ptr,
                                                        const int* __restrict__ csr_src,
                                                        const float* __restrict__ dis,
                                                        const float* __restrict__ b,
                                                        float* __restrict__ out, int n) {
    int node = blockIdx.x * 4 + (threadIdx.x >> 6);
    if (node >= n) return;
    int lane = threadIdx.x & 63;

    float2 s0 = __half22float2(Hs[(size_t)node * 64 + lane]);
    float accx = s0.x, accy = s0.y;                     // self-loop term H'[i]

    int p0 = row_ptr[node], p1 = row_ptr[node + 1];
    int p = p0;
    int nb8 = (p1 - p0) >> 3;
    if (nb8 > 0) {
        int idx[8];
#pragma unroll
        for (int u = 0; u < 8; ++u) idx[u] = csr_src[p + u];
        for (int bb = 1; bb < nb8; ++bb) {
            int nxt[8];
#pragma unroll
            for (int u = 0; u < 8; ++u) nxt[u] = csr_src[p + 8 + u];   // prefetch
            __half2 v[8];
#pragma unroll
            for (int u = 0; u < 8; ++u) v[u] = Hs[(size_t)idx[u] * 64 + lane];
#pragma unroll
            for (int u = 0; u < 8; ++u) {
                float2 f = __half22float2(v[u]);
                accx += f.x; accy += f.y;
            }
#pragma unroll
            for (int u = 0; u < 8; ++u) idx[u] = nxt[u];
            p += 8;
        }
        {
            __half2 v[8];
#pragma unroll
            for (int u = 0; u < 8; ++u) v[u] = Hs[(size_t)idx[u] * 64 + lane];
#pragma unroll
            for (int u = 0; u < 8; ++u) {
                float2 f = __half22float2(v[u]);
                accx += f.x; accy += f.y;
            }
            p += 8;
        }
    }
    // tail (< 8 edges)
    for (; p + 4 <= p1; p += 4) {
        int s0i = csr_src[p + 0];
        int s1i = csr_src[p + 1];
        int s2i = csr_src[p + 2];
        int s3i = csr_src[p + 3];
        __half2 v0 = Hs[(size_t)s0i * 64 + lane];
        __half2 v1 = Hs[(size_t)s1i * 64 + lane];
        __half2 v2 = Hs[(size_t)s2i * 64 + lane];
        __half2 v3 = Hs[(size_t)s3i * 64 + lane];
        float2 f0 = __half22float2(v0), f1 = __half22float2(v1);
        float2 f2 = __half22float2(v2), f3 = __half22float2(v3);
        accx += f0.x; accy += f0.y;
        accx += f1.x; accy += f1.y;
        accx += f2.x; accy += f2.y;
        accx += f3.x; accy += f3.y;
    }
    for (; p < p1; ++p) {
        int s = csr_src[p];
        float2 f = __half22float2(Hs[(size_t)s * 64 + lane]);
        accx += f.x; accy += f.y;
    }

    float di = dis[node];
    float2 bb2 = *(const float2*)(b + 2 * lane);
    float2 o;
    o.x = fmaf(accx, di, bb2.x);
    o.y = fmaf(accy, di, bb2.y);
    ((float2*)(out + (size_t)node * D))[lane] = o;
}

// ---------------- launch ----------------

extern "C" void kernel_launch(void* const* d_in, const int* in_sizes, int n_in,
                              void* d_out, int out_size, void* d_ws, size_t ws_size,
                              hipStream_t stream) {
    const float* x  = (const float*)d_in[0];
    const int*   ei = (const int*)d_in[1];
    const float* W1 = (const float*)d_in[2];
    const float* b1 = (const float*)d_in[3];
    const float* W2 = (const float*)d_in[4];
    const float* b2 = (const float*)d_in[5];
    const float* W3 = (const float*)d_in[6];
    const float* b3 = (const float*)d_in[7];
    float* out = (float*)d_out;

    int n = in_sizes[0] / D;
    int E = in_sizes[1] / 2;
    const int* src = ei;
    const int* dst = ei + E;
    int K = (n + NPB - 1) >> 8;     // buckets

    char* ws = (char*)d_ws;
    __half* hbuf     = (__half*)ws; ws += (size_t)n * D * sizeof(float); // fp16 H' (uses half the region)
    float* dis       = (float*)ws;  ws += (size_t)n * sizeof(float);
    int* row_ptr     = (int*)ws;    ws += (size_t)(n + 1) * sizeof(int);
    int* csr_src     = (int*)ws;    ws += (size_t)E * sizeof(int);
    int* bucket_cnt  = (int*)ws;    ws += KMAX * sizeof(int);
    int* bucket_ptr  = (int*)ws;    ws += (KMAX + 1) * sizeof(int);
    int* bucket_cur  = (int*)ws;    ws += KMAX * sizeof(int);
    int2* bdata      = (int2*)hbuf;   // aliases hbuf; dead before first GEMM writes it

    int gC = (E + CHUNK - 1) / CHUNK; // 391
    int gM = (n + 127) / 128;         // 782
    int gA = (n + 3) / 4;             // 25000

    // CSR build — no per-node global atomics anywhere.
    zero_int<<<2, 256, 0, stream>>>(bucket_cnt, KMAX);
    bucket_hist_kernel<<<gC, 256, 0, stream>>>(dst, bucket_cnt, E);
    bucket_scan_kernel<<<1, KMAX, 0, stream>>>(bucket_cnt, bucket_ptr, bucket_cur, K, E);
    bucket_scatter_kernel<<<gC, 256, 0, stream>>>(src, dst, bucket_cur, bdata, E);
    csr_count_scan_kernel<<<K, 256, 0, stream>>>(bdata, bucket_ptr, row_ptr, dis, n, E, K);
    csr_fill_kernel<<<K, 256, 0, stream>>>(bdata, bucket_ptr, row_ptr, csr_src, n);

    // Layer 1: H' = fp16(dis*(x@W1)) -> hbuf ; agg+b1 -> out
    gemm_kernel<false><<<gM, 256, 0, stream>>>(x, W1, dis, hbuf, n);
    aggregate_kernel<<<gA, 256, 0, stream>>>((const __half2*)hbuf, row_ptr, csr_src, dis, b1, out, n);
    // Layer 2: H' = fp16(dis*(relu(out)@W2)) -> hbuf ; agg+b2 -> out
    gemm_kernel<true><<<gM, 256, 0, stream>>>(out, W2, dis, hbuf, n);
    aggregate_kernel<<<gA, 256, 0, stream>>>((const __half2*)hbuf, row_ptr, csr_src, dis, b2, out, n);
    // Layer 3: H' = fp16(dis*(relu(out)@W3)) -> hbuf ; agg+b3 -> out
    gemm_kernel<true><<<gM, 256, 0, stream>>>(out, W3, dis, hbuf, n);
    aggregate_kernel<<<gA, 256, 0, stream>>>((const __half2*)hbuf, row_ptr, csr_src, dis, b3, out, n);
}

// Round 3
// 455.889 us; speedup vs baseline: 1.5518x; 1.2014x over previous
//
#include <hip/hip_runtime.h>
#include <hip/hip_fp16.h>

#define D 128
#define NPB 256          // nodes per bucket (dst >> 8)
#define KMAX 512         // max buckets (n <= 131072)
#define CHUNK 4096       // edges per block in bucket passes

typedef _Float16 half_t;
typedef _Float16 f16x8 __attribute__((ext_vector_type(8)));
typedef float f32x4 __attribute__((ext_vector_type(4)));

// ---------------- CSR build ----------------

__global__ __launch_bounds__(256) void zero_int(int* __restrict__ p, int n) {
    int i = blockIdx.x * 256 + threadIdx.x;
    if (i < n) p[i] = 0;
}

__global__ __launch_bounds__(256) void bucket_hist_kernel(const int* __restrict__ dst,
                                                          int* __restrict__ bucket_cnt, int E) {
    __shared__ int scnt[KMAX];
    int t = threadIdx.x;
    for (int i = t; i < KMAX; i += 256) scnt[i] = 0;
    __syncthreads();
    int base = blockIdx.x * CHUNK;
    int nE = min(CHUNK, E - base);
    for (int i = t; i < nE; i += 256)
        atomicAdd(&scnt[dst[base + i] >> 8], 1);
    __syncthreads();
    for (int i = t; i < KMAX; i += 256)
        if (scnt[i]) atomicAdd(&bucket_cnt[i], scnt[i]);
}

__global__ __launch_bounds__(KMAX) void bucket_scan_kernel(const int* __restrict__ bucket_cnt,
                                                           int* __restrict__ bucket_ptr,
                                                           int* __restrict__ bucket_cur,
                                                           int K, int E) {
    __shared__ int sh[KMAX];
    int t = threadIdx.x;
    int v = (t < K) ? bucket_cnt[t] : 0;
    sh[t] = v;
    __syncthreads();
    for (int off = 1; off < KMAX; off <<= 1) {
        int add = (t >= off) ? sh[t - off] : 0;
        __syncthreads();
        sh[t] += add;
        __syncthreads();
    }
    if (t < K) {
        int ex = sh[t] - v;
        bucket_ptr[t] = ex;
        bucket_cur[t] = ex;
    }
    if (t == 0) bucket_ptr[K] = E;
}

__global__ __launch_bounds__(256) void bucket_scatter_kernel(const int* __restrict__ src,
                                                             const int* __restrict__ dst,
                                                             int* __restrict__ bucket_cur,
                                                             int2* __restrict__ bdata, int E) {
    __shared__ int sdst[CHUNK];     // 16 KB
    __shared__ int scnt[KMAX];      // 2 KB
    __shared__ int sbase[KMAX];     // 2 KB
    int t = threadIdx.x;
    int base = blockIdx.x * CHUNK;
    int nE = min(CHUNK, E - base);
    for (int i = t; i < KMAX; i += 256) scnt[i] = 0;
    __syncthreads();
    for (int i = t; i < nE; i += 256) {
        int d = dst[base + i];
        sdst[i] = d;
        atomicAdd(&scnt[d >> 8], 1);
    }
    __syncthreads();
    for (int i = t; i < KMAX; i += 256) {
        int c = scnt[i];
        sbase[i] = c ? atomicAdd(&bucket_cur[i], c) : 0;
        scnt[i] = 0;                // reuse as local cursor
    }
    __syncthreads();
    for (int i = t; i < nE; i += 256) {
        int d = sdst[i];
        int b = d >> 8;
        int pos = sbase[b] + atomicAdd(&scnt[b], 1);
        bdata[pos] = make_int2(src[base + i], d);
    }
}

__global__ __launch_bounds__(256) void csr_count_scan_kernel(const int2* __restrict__ bdata,
                                                             const int* __restrict__ bucket_ptr,
                                                             int* __restrict__ row_ptr,
                                                             float* __restrict__ dis,
                                                             int n, int E, int K) {
    __shared__ int scnt[NPB];
    __shared__ int sh[NPB];
    int b = blockIdx.x;
    int node0 = b << 8;
    int nn = min(NPB, n - node0);
    int t = threadIdx.x;
    scnt[t] = 0;
    __syncthreads();
    int p0 = bucket_ptr[b], p1 = bucket_ptr[b + 1];
    for (int i = p0 + t; i < p1; i += 256)
        atomicAdd(&scnt[bdata[i].y - node0], 1);
    __syncthreads();
    int v = scnt[t];
    sh[t] = v;
    __syncthreads();
    for (int off = 1; off < NPB; off <<= 1) {
        int add = (t >= off) ? sh[t - off] : 0;
        __syncthreads();
        sh[t] += add;
        __syncthreads();
    }
    if (t < nn) {
        row_ptr[node0 + t] = p0 + sh[t] - v;     // exclusive
        dis[node0 + t] = rsqrtf((float)(v + 1)); // +1 self-loop
    }
    if (b == K - 1 && t == 0) row_ptr[n] = E;
}

__global__ __launch_bounds__(256) void csr_fill_kernel(const int2* __restrict__ bdata,
                                                       const int* __restrict__ bucket_ptr,
                                                       const int* __restrict__ row_ptr,
                                                       int* __restrict__ csr_src, int n) {
    __shared__ int cursor[NPB];
    int b = blockIdx.x;
    int node0 = b << 8;
    int nn = min(NPB, n - node0);
    int t = threadIdx.x;
    if (t < nn) cursor[t] = row_ptr[node0 + t];
    __syncthreads();
    int p0 = bucket_ptr[b], p1 = bucket_ptr[b + 1];
    for (int i = p0 + t; i < p1; i += 256) {
        int2 e = bdata[i];
        int pos = atomicAdd(&cursor[e.y - node0], 1);
        csr_src[pos] = e.x;
    }
}

// ---------------- W pre-pack: fp32 [128][128] -> fp16 per-lane MFMA frag order ----
// Wf[((s*8 + t)*64 + l)*8 + j] = W[k][n], k = s*32 + 4*(l>>4) + (j&3) + 16*(j>>2),
// n = t*16 + (l&15). Same K-mapping is used for the A-fragments in the GEMM, so
// any error in the assumed per-lane K layout is a consistent permutation of the
// contraction index and cancels.

__global__ __launch_bounds__(256) void pack_w_kernel(const float* __restrict__ W,
                                                     half_t* __restrict__ Wf) {
    int b = blockIdx.x;           // 0..31 = (s,t)
    int s = b >> 3, t = b & 7;
    int tid = threadIdx.x;
    for (int e = tid; e < 512; e += 256) {
        int l = e >> 3, j = e & 7;
        int k = s * 32 + ((l >> 4) & 3) * 4 + (j & 3) + ((j >> 2) << 4);
        int n = t * 16 + (l & 15);
        Wf[(size_t)((s * 8 + t) * 64 + l) * 8 + j] = (half_t)W[k * 128 + n];
    }
}

// ---------------- GEMM (MFMA): C[n x 128] = fp16( dis[row] * ((relu?)A @ W) ) ----
// R9: fp16 MFMA (16x16x32). Block = 64 rows x 128 cols, 4 waves x (M=16,N=128).
// A staged fp32->fp16 in LDS (64x132 halves, 16.9 KB -> 8 blocks/CU).
// W fragments streamed from the pre-packed Wf (L1/L2-hot, one dwordx4 per MFMA).
// Compute ~2 us; kernel is a pure streaming pass: read A (51 MB) + write C (26 MB).

template <bool RELU>
__global__ __launch_bounds__(256) void gemm_mfma_kernel(const float* __restrict__ A,
                                                        const half_t* __restrict__ Wf,
                                                        const float* __restrict__ dis,
                                                        half_t* __restrict__ C, int n) {
    __shared__ half_t sA[64 * 132];      // 16896 B, +4 halves row pad
    int tid = threadIdx.x;
    int base = blockIdx.x * 64;

    // ---- stage A tile as fp16 (8 float4 per thread) ----
    const float4* A4 = (const float4*)A;     // row stride = 32 float4
#pragma unroll
    for (int it = 0; it < 8; ++it) {
        int idx = it * 256 + tid;            // 0..2047
        int r = idx >> 5, kq = idx & 31;
        int grow = base + r;
        float4 va = (grow < n) ? A4[(size_t)grow * 32 + kq]
                               : make_float4(0.f, 0.f, 0.f, 0.f);
        if (RELU) {
            va.x = fmaxf(va.x, 0.f); va.y = fmaxf(va.y, 0.f);
            va.z = fmaxf(va.z, 0.f); va.w = fmaxf(va.w, 0.f);
        }
        union { half_t h[4]; float2 f2; } pk;
        pk.h[0] = (half_t)va.x; pk.h[1] = (half_t)va.y;
        pk.h[2] = (half_t)va.z; pk.h[3] = (half_t)va.w;
        *(float2*)&sA[r * 132 + kq * 4] = pk.f2;
    }
    __syncthreads();

    int l = tid & 63, w = tid >> 6;      // lane, wave
    int m = l & 15, g = l >> 4;          // frag row (M), k-group
    int R = w * 16;                      // wave's row base within tile

    f32x4 acc[8];
#pragma unroll
    for (int t = 0; t < 8; ++t) acc[t] = (f32x4){0.f, 0.f, 0.f, 0.f};

    const f16x8* WF = (const f16x8*)Wf;
#pragma unroll
    for (int s = 0; s < 4; ++s) {        // K steps of 32
        union { f16x8 v; float2 f2[2]; } af;
        int a_off = (R + m) * 132 + s * 32 + 4 * g;
        af.f2[0] = *(const float2*)&sA[a_off];        // k-offsets +0..3
        af.f2[1] = *(const float2*)&sA[a_off + 16];   // k-offsets +16..19
#pragma unroll
        for (int t = 0; t < 8; ++t) {
            f16x8 bf = WF[(size_t)(s * 8 + t) * 64 + l];
            acc[t] = __builtin_amdgcn_mfma_f32_16x16x32_f16(af.v, bf, acc[t], 0, 0, 0);
        }
    }

    // ---- epilogue: D layout col = l&15, row = 4*(l>>4) + reg (m89-verified) ----
    int row0 = base + R + 4 * g;
    float dd[4];
#pragma unroll
    for (int r = 0; r < 4; ++r) dd[r] = (row0 + r < n) ? dis[row0 + r] : 0.f;
#pragma unroll
    for (int t = 0; t < 8; ++t) {
        int col = t * 16 + m;
#pragma unroll
        for (int r = 0; r < 4; ++r) {
            int row = row0 + r;
            if (row < n) C[(size_t)row * D + col] = (half_t)(acc[t][r] * dd[r]);
        }
    }
}

// ---------------- Aggregation: out[i] = dis_i*(H'[i] + sum_e H'[src_e]) + b ----------
// H' fp16 (256B rows), one half2 per lane, fp32 accumulation, batch-8 gather
// pipeline with next-batch index prefetch.

__global__ __launch_bounds__(256) void aggregate_kernel(const __half2* __restrict__ Hs,
                                                        const int* __restrict__ row_ptr,
                                                        const int* __restrict__ csr_src,
                                                        const float* __restrict__ dis,
                                                        const float* __restrict__ b,
                                                        float* __restrict__ out, int n) {
    int node = blockIdx.x * 4 + (threadIdx.x >> 6);
    if (node >= n) return;
    int lane = threadIdx.x & 63;

    float2 s0 = __half22float2(Hs[(size_t)node * 64 + lane]);
    float accx = s0.x, accy = s0.y;                     // self-loop term H'[i]

    int p0 = row_ptr[node], p1 = row_ptr[node + 1];
    int p = p0;
    int nb8 = (p1 - p0) >> 3;
    if (nb8 > 0) {
        int idx[8];
#pragma unroll
        for (int u = 0; u < 8; ++u) idx[u] = csr_src[p + u];
        for (int bb = 1; bb < nb8; ++bb) {
            int nxt[8];
#pragma unroll
            for (int u = 0; u < 8; ++u) nxt[u] = csr_src[p + 8 + u];   // prefetch
            __half2 v[8];
#pragma unroll
            for (int u = 0; u < 8; ++u) v[u] = Hs[(size_t)idx[u] * 64 + lane];
#pragma unroll
            for (int u = 0; u < 8; ++u) {
                float2 f = __half22float2(v[u]);
                accx += f.x; accy += f.y;
            }
#pragma unroll
            for (int u = 0; u < 8; ++u) idx[u] = nxt[u];
            p += 8;
        }
        {
            __half2 v[8];
#pragma unroll
            for (int u = 0; u < 8; ++u) v[u] = Hs[(size_t)idx[u] * 64 + lane];
#pragma unroll
            for (int u = 0; u < 8; ++u) {
                float2 f = __half22float2(v[u]);
                accx += f.x; accy += f.y;
            }
            p += 8;
        }
    }
    for (; p + 4 <= p1; p += 4) {
        int s0i = csr_src[p + 0];
        int s1i = csr_src[p + 1];
        int s2i = csr_src[p + 2];
        int s3i = csr_src[p + 3];
        __half2 v0 = Hs[(size_t)s0i * 64 + lane];
        __half2 v1 = Hs[(size_t)s1i * 64 + lane];
        __half2 v2 = Hs[(size_t)s2i * 64 + lane];
        __half2 v3 = Hs[(size_t)s3i * 64 + lane];
        float2 f0 = __half22float2(v0), f1 = __half22float2(v1);
        float2 f2 = __half22float2(v2), f3 = __half22float2(v3);
        accx += f0.x; accy += f0.y;
        accx += f1.x; accy += f1.y;
        accx += f2.x; accy += f2.y;
        accx += f3.x; accy += f3.y;
    }
    for (; p < p1; ++p) {
        int s = csr_src[p];
        float2 f = __half22float2(Hs[(size_t)s * 64 + lane]);
        accx += f.x; accy += f.y;
    }

    float di = dis[node];
    float2 bb2 = *(const float2*)(b + 2 * lane);
    float2 o;
    o.x = fmaf(accx, di, bb2.x);
    o.y = fmaf(accy, di, bb2.y);
    ((float2*)(out + (size_t)node * D))[lane] = o;
}

// ---------------- launch ----------------

extern "C" void kernel_launch(void* const* d_in, const int* in_sizes, int n_in,
                              void* d_out, int out_size, void* d_ws, size_t ws_size,
                              hipStream_t stream) {
    const float* x  = (const float*)d_in[0];
    const int*   ei = (const int*)d_in[1];
    const float* W1 = (const float*)d_in[2];
    const float* b1 = (const float*)d_in[3];
    const float* W2 = (const float*)d_in[4];
    const float* b2 = (const float*)d_in[5];
    const float* W3 = (const float*)d_in[6];
    const float* b3 = (const float*)d_in[7];
    float* out = (float*)d_out;

    int n = in_sizes[0] / D;
    int E = in_sizes[1] / 2;
    const int* src = ei;
    const int* dst = ei + E;
    int K = (n + NPB - 1) >> 8;     // buckets

    char* ws = (char*)d_ws;
    half_t* hbuf     = (half_t*)ws; ws += (size_t)n * D * sizeof(float); // region sized fp32; fp16 uses half
    float* dis       = (float*)ws;  ws += (size_t)n * sizeof(float);
    int* row_ptr     = (int*)ws;    ws += (size_t)(n + 1) * sizeof(int);
    int* csr_src     = (int*)ws;    ws += (size_t)E * sizeof(int);
    int* bucket_cnt  = (int*)ws;    ws += KMAX * sizeof(int);
    int* bucket_ptr  = (int*)ws;    ws += (KMAX + 1) * sizeof(int);
    int* bucket_cur  = (int*)ws;    ws += KMAX * sizeof(int);
    int2* bdata      = (int2*)hbuf;                 // [0, 12.8 MB): dead before GEMM1 writes hbuf
    half_t* Wf1      = hbuf + (size_t)n * D;        // [25.6 MB, +32 KB): unused half of hbuf region
    half_t* Wf2      = Wf1 + 128 * 128;
    half_t* Wf3      = Wf2 + 128 * 128;

    int gC = (E + CHUNK - 1) / CHUNK; // 391
    int gM = (n + 63) / 64;           // 1563
    int gA = (n + 3) / 4;             // 25000

    // W pre-pack (fp16 frag order), then CSR build.
    pack_w_kernel<<<32, 256, 0, stream>>>(W1, Wf1);
    pack_w_kernel<<<32, 256, 0, stream>>>(W2, Wf2);
    pack_w_kernel<<<32, 256, 0, stream>>>(W3, Wf3);

    zero_int<<<2, 256, 0, stream>>>(bucket_cnt, KMAX);
    bucket_hist_kernel<<<gC, 256, 0, stream>>>(dst, bucket_cnt, E);
    bucket_scan_kernel<<<1, KMAX, 0, stream>>>(bucket_cnt, bucket_ptr, bucket_cur, K, E);
    bucket_scatter_kernel<<<gC, 256, 0, stream>>>(src, dst, bucket_cur, bdata, E);
    csr_count_scan_kernel<<<K, 256, 0, stream>>>(bdata, bucket_ptr, row_ptr, dis, n, E, K);
    csr_fill_kernel<<<K, 256, 0, stream>>>(bdata, bucket_ptr, row_ptr, csr_src, n);

    // Layer 1: H' = fp16(dis*(x@W1)) -> hbuf ; agg+b1 -> out
    gemm_mfma_kernel<false><<<gM, 256, 0, stream>>>(x, Wf1, dis, hbuf, n);
    aggregate_kernel<<<gA, 256, 0, stream>>>((const __half2*)hbuf, row_ptr, csr_src, dis, b1, out, n);
    // Layer 2: H' = fp16(dis*(relu(out)@W2)) -> hbuf ; agg+b2 -> out
    gemm_mfma_kernel<true><<<gM, 256, 0, stream>>>(out, Wf2, dis, hbuf, n);
    aggregate_kernel<<<gA, 256, 0, stream>>>((const __half2*)hbuf, row_ptr, csr_src, dis, b2, out, n);
    // Layer 3: H' = fp16(dis*(relu(out)@W3)) -> hbuf ; agg+b3 -> out
    gemm_mfma_kernel<true><<<gM, 256, 0, stream>>>(out, Wf3, dis, hbuf, n);
    aggregate_kernel<<<gA, 256, 0, stream>>>((const __half2*)hbuf, row_ptr, csr_src, dis, b3, out, n);
}

// Round 5
// 421.943 us; speedup vs baseline: 1.6766x; 1.0805x over previous
//
#include <hip/hip_runtime.h>
#include <hip/hip_fp16.h>

#define D 128
#define TPAD 136         // halves; 272B row stride: 16B-aligned, 2-way bank alias (free)
#define NPB 256          // nodes per bucket (dst >> 8)
#define KMAX 512         // max buckets (n <= 131072)
#define CHUNK 4096       // edges per block in bucket passes

typedef _Float16 half_t;
typedef _Float16 f16x8 __attribute__((ext_vector_type(8)));
typedef float f32x4 __attribute__((ext_vector_type(4)));

// ---------------- CSR build ----------------

__global__ __launch_bounds__(256) void zero_int(int* __restrict__ p, int n) {
    int i = blockIdx.x * 256 + threadIdx.x;
    if (i < n) p[i] = 0;
}

__global__ __launch_bounds__(256) void bucket_hist_kernel(const int* __restrict__ dst,
                                                          int* __restrict__ bucket_cnt, int E) {
    __shared__ int scnt[KMAX];
    int t = threadIdx.x;
    for (int i = t; i < KMAX; i += 256) scnt[i] = 0;
    __syncthreads();
    int base = blockIdx.x * CHUNK;
    int nE = min(CHUNK, E - base);
    for (int i = t; i < nE; i += 256)
        atomicAdd(&scnt[dst[base + i] >> 8], 1);
    __syncthreads();
    for (int i = t; i < KMAX; i += 256)
        if (scnt[i]) atomicAdd(&bucket_cnt[i], scnt[i]);
}

__global__ __launch_bounds__(KMAX) void bucket_scan_kernel(const int* __restrict__ bucket_cnt,
                                                           int* __restrict__ bucket_ptr,
                                                           int* __restrict__ bucket_cur,
                                                           int K, int E) {
    __shared__ int sh[KMAX];
    int t = threadIdx.x;
    int v = (t < K) ? bucket_cnt[t] : 0;
    sh[t] = v;
    __syncthreads();
    for (int off = 1; off < KMAX; off <<= 1) {
        int add = (t >= off) ? sh[t - off] : 0;
        __syncthreads();
        sh[t] += add;
        __syncthreads();
    }
    if (t < K) {
        int ex = sh[t] - v;
        bucket_ptr[t] = ex;
        bucket_cur[t] = ex;
    }
    if (t == 0) bucket_ptr[K] = E;
}

__global__ __launch_bounds__(256) void bucket_scatter_kernel(const int* __restrict__ src,
                                                             const int* __restrict__ dst,
                                                             int* __restrict__ bucket_cur,
                                                             int2* __restrict__ bdata, int E) {
    __shared__ int sdst[CHUNK];     // 16 KB
    __shared__ int scnt[KMAX];      // 2 KB
    __shared__ int sbase[KMAX];     // 2 KB
    int t = threadIdx.x;
    int base = blockIdx.x * CHUNK;
    int nE = min(CHUNK, E - base);
    for (int i = t; i < KMAX; i += 256) scnt[i] = 0;
    __syncthreads();
    for (int i = t; i < nE; i += 256) {
        int d = dst[base + i];
        sdst[i] = d;
        atomicAdd(&scnt[d >> 8], 1);
    }
    __syncthreads();
    for (int i = t; i < KMAX; i += 256) {
        int c = scnt[i];
        sbase[i] = c ? atomicAdd(&bucket_cur[i], c) : 0;
        scnt[i] = 0;                // reuse as local cursor
    }
    __syncthreads();
    for (int i = t; i < nE; i += 256) {
        int d = sdst[i];
        int b = d >> 8;
        int pos = sbase[b] + atomicAdd(&scnt[b], 1);
        bdata[pos] = make_int2(src[base + i], d);
    }
}

__global__ __launch_bounds__(256) void csr_count_scan_kernel(const int2* __restrict__ bdata,
                                                             const int* __restrict__ bucket_ptr,
                                                             int* __restrict__ row_ptr,
                                                             float* __restrict__ dis,
                                                             int n, int E, int K) {
    __shared__ int scnt[NPB];
    __shared__ int sh[NPB];
    int b = blockIdx.x;
    int node0 = b << 8;
    int nn = min(NPB, n - node0);
    int t = threadIdx.x;
    scnt[t] = 0;
    __syncthreads();
    int p0 = bucket_ptr[b], p1 = bucket_ptr[b + 1];
    for (int i = p0 + t; i < p1; i += 256)
        atomicAdd(&scnt[bdata[i].y - node0], 1);
    __syncthreads();
    int v = scnt[t];
    sh[t] = v;
    __syncthreads();
    for (int off = 1; off < NPB; off <<= 1) {
        int add = (t >= off) ? sh[t - off] : 0;
        __syncthreads();
        sh[t] += add;
        __syncthreads();
    }
    if (t < nn) {
        row_ptr[node0 + t] = p0 + sh[t] - v;     // exclusive
        dis[node0 + t] = rsqrtf((float)(v + 1)); // +1 self-loop
    }
    if (b == K - 1 && t == 0) row_ptr[n] = E;
}

__global__ __launch_bounds__(256) void csr_fill_kernel(const int2* __restrict__ bdata,
                                                       const int* __restrict__ bucket_ptr,
                                                       const int* __restrict__ row_ptr,
                                                       int* __restrict__ csr_src, int n) {
    __shared__ int cursor[NPB];
    int b = blockIdx.x;
    int node0 = b << 8;
    int nn = min(NPB, n - node0);
    int t = threadIdx.x;
    if (t < nn) cursor[t] = row_ptr[node0 + t];
    __syncthreads();
    int p0 = bucket_ptr[b], p1 = bucket_ptr[b + 1];
    for (int i = p0 + t; i < p1; i += 256) {
        int2 e = bdata[i];
        int pos = atomicAdd(&cursor[e.y - node0], 1);
        csr_src[pos] = e.x;
    }
}

// ---------------- W pre-pack: fp32 [128][128] -> fp16 per-lane MFMA frag order ----
// Wf[((s*8 + t)*64 + l)*8 + j] = W[k][n], k = s*32 + 4*((l>>4)&3) + (j&3) + 16*(j>>2),
// n = t*16 + (l&15). Same K-mapping as the A-fragments; any K-layout error is a
// consistent permutation of the contraction index and cancels.

__global__ __launch_bounds__(256) void pack_w_kernel(const float* __restrict__ W,
                                                     half_t* __restrict__ Wf) {
    int b = blockIdx.x;           // 0..31 = (s,t)
    int s = b >> 3, t = b & 7;
    int tid = threadIdx.x;
    for (int e = tid; e < 512; e += 256) {
        int l = e >> 3, j = e & 7;
        int k = s * 32 + ((l >> 4) & 3) * 4 + (j & 3) + ((j >> 2) << 4);
        int n = t * 16 + (l & 15);
        Wf[(size_t)((s * 8 + t) * 64 + l) * 8 + j] = (half_t)W[k * 128 + n];
    }
}

// ---------------- GEMM (MFMA): C[n x 128] = fp16( dis[row] * (A @ W) ) ----------
// R11 (=R10 fixed): epilogue bounces acc through LDS (tile dead after K-loop),
// stores C as contiguous float4 — 4 iterations x 256 threads = 1024 float4 =
// the full 64x128 fp16 tile (R10 bug: only 2 iterations -> rows 32-63 never
// written -> NaN from the bdata alias).

__device__ __forceinline__ void gemm_core_epilogue(half_t* sA, int tid, int base,
                                                   const float* __restrict__ dis,
                                                   half_t* __restrict__ C, int n,
                                                   f32x4 acc[8], int l, int w) {
    int m = l & 15, g = l >> 4;
    int R = w * 16;
    int row0 = base + R + 4 * g;
    float dd[4];
#pragma unroll
    for (int r = 0; r < 4; ++r) dd[r] = (row0 + r < n) ? dis[row0 + r] : 0.f;
    __syncthreads();            // all frag reads done before clobbering sA
#pragma unroll
    for (int t = 0; t < 8; ++t) {
#pragma unroll
        for (int r = 0; r < 4; ++r)
            sA[(R + 4 * g + r) * TPAD + t * 16 + m] = (half_t)(acc[t][r] * dd[r]);
    }
    __syncthreads();
#pragma unroll
    for (int q = 0; q < 4; ++q) {
        int f4 = q * 256 + tid;         // 0..1023 ; 16 float4 per row, 64 rows
        int r = f4 >> 4, c = f4 & 15;
        int row = base + r;
        if (row < n)
            *(float4*)&C[(size_t)row * D + c * 8] = *(const float4*)&sA[r * TPAD + c * 8];
    }
}

__device__ __forceinline__ void gemm_mfma_loop(const half_t* sA, const half_t* __restrict__ Wf,
                                               f32x4 acc[8], int l, int w) {
    int m = l & 15, g = l >> 4;
    int R = w * 16;
    const f16x8* WF = (const f16x8*)Wf;
#pragma unroll
    for (int s = 0; s < 4; ++s) {        // K steps of 32
        union { f16x8 v; float2 f2[2]; } af;
        int a_off = (R + m) * TPAD + s * 32 + 4 * g;
        af.f2[0] = *(const float2*)&sA[a_off];        // k +0..3
        af.f2[1] = *(const float2*)&sA[a_off + 16];   // k +16..19
#pragma unroll
        for (int t = 0; t < 8; ++t) {
            f16x8 bf = WF[(size_t)(s * 8 + t) * 64 + l];
            acc[t] = __builtin_amdgcn_mfma_f32_16x16x32_f16(af.v, bf, acc[t], 0, 0, 0);
        }
    }
}

__global__ __launch_bounds__(256) void gemm_mfma_f32in(const float* __restrict__ A,
                                                       const half_t* __restrict__ Wf,
                                                       const float* __restrict__ dis,
                                                       half_t* __restrict__ C, int n) {
    __shared__ half_t sA[64 * TPAD];
    int tid = threadIdx.x;
    int base = blockIdx.x * 64;

    const float4* A4 = (const float4*)A;     // row stride = 32 float4
#pragma unroll
    for (int it = 0; it < 8; ++it) {
        int idx = it * 256 + tid;            // 0..2047
        int r = idx >> 5, kq = idx & 31;
        int grow = base + r;
        float4 va = (grow < n) ? A4[(size_t)grow * 32 + kq]
                               : make_float4(0.f, 0.f, 0.f, 0.f);
        union { half_t h[4]; float2 f2; } pk;
        pk.h[0] = (half_t)va.x; pk.h[1] = (half_t)va.y;
        pk.h[2] = (half_t)va.z; pk.h[3] = (half_t)va.w;
        *(float2*)&sA[r * TPAD + kq * 4] = pk.f2;
    }
    __syncthreads();

    int l = tid & 63, w = tid >> 6;
    f32x4 acc[8];
#pragma unroll
    for (int t = 0; t < 8; ++t) acc[t] = (f32x4){0.f, 0.f, 0.f, 0.f};
    gemm_mfma_loop(sA, Wf, acc, l, w);
    gemm_core_epilogue(sA, tid, base, dis, C, n, acc, l, w);
}

__global__ __launch_bounds__(256) void gemm_mfma_f16in(const half_t* __restrict__ A,
                                                       const half_t* __restrict__ Wf,
                                                       const float* __restrict__ dis,
                                                       half_t* __restrict__ C, int n) {
    __shared__ half_t sA[64 * TPAD];
    int tid = threadIdx.x;
    int base = blockIdx.x * 64;

    const float4* A4 = (const float4*)A;     // fp16 row = 16 float4
#pragma unroll
    for (int it = 0; it < 4; ++it) {
        int idx = it * 256 + tid;            // 0..1023
        int r = idx >> 4, c16 = idx & 15;
        int grow = base + r;
        float4 va = (grow < n) ? A4[(size_t)grow * 16 + c16]
                               : make_float4(0.f, 0.f, 0.f, 0.f);
        *(float4*)&sA[r * TPAD + c16 * 8] = va;
    }
    __syncthreads();

    int l = tid & 63, w = tid >> 6;
    f32x4 acc[8];
#pragma unroll
    for (int t = 0; t < 8; ++t) acc[t] = (f32x4){0.f, 0.f, 0.f, 0.f};
    gemm_mfma_loop(sA, Wf, acc, l, w);
    gemm_core_epilogue(sA, tid, base, dis, C, n, acc, l, w);
}

// ---------------- Aggregation: out[i] = dis_i*(H'[i] + sum_e H'[src_e]) + b ----------
// H' fp16 (256B rows), one half2 per lane, fp32 accumulation, batch-8 gather
// pipeline with next-batch index prefetch. F16OUT: write relu'd fp16 (layers
// 1-2; consumed only by the next GEMM) — halves the write traffic.

template <bool F16OUT>
__global__ __launch_bounds__(256) void aggregate_kernel(const __half2* __restrict__ Hs,
                                                        const int* __restrict__ row_ptr,
                                                        const int* __restrict__ csr_src,
                                                        const float* __restrict__ dis,
                                                        const float* __restrict__ b,
                                                        void* __restrict__ outv, int n) {
    int node = blockIdx.x * 4 + (threadIdx.x >> 6);
    if (node >= n) return;
    int lane = threadIdx.x & 63;

    float2 s0 = __half22float2(Hs[(size_t)node * 64 + lane]);
    float accx = s0.x, accy = s0.y;                     // self-loop term H'[i]

    int p0 = row_ptr[node], p1 = row_ptr[node + 1];
    int p = p0;
    int nb8 = (p1 - p0) >> 3;
    if (nb8 > 0) {
        int idx[8];
#pragma unroll
        for (int u = 0; u < 8; ++u) idx[u] = csr_src[p + u];
        for (int bb = 1; bb < nb8; ++bb) {
            int nxt[8];
#pragma unroll
            for (int u = 0; u < 8; ++u) nxt[u] = csr_src[p + 8 + u];   // prefetch
            __half2 v[8];
#pragma unroll
            for (int u = 0; u < 8; ++u) v[u] = Hs[(size_t)idx[u] * 64 + lane];
#pragma unroll
            for (int u = 0; u < 8; ++u) {
                float2 f = __half22float2(v[u]);
                accx += f.x; accy += f.y;
            }
#pragma unroll
            for (int u = 0; u < 8; ++u) idx[u] = nxt[u];
            p += 8;
        }
        {
            __half2 v[8];
#pragma unroll
            for (int u = 0; u < 8; ++u) v[u] = Hs[(size_t)idx[u] * 64 + lane];
#pragma unroll
            for (int u = 0; u < 8; ++u) {
                float2 f = __half22float2(v[u]);
                accx += f.x; accy += f.y;
            }
            p += 8;
        }
    }
    for (; p + 4 <= p1; p += 4) {
        int s0i = csr_src[p + 0];
        int s1i = csr_src[p + 1];
        int s2i = csr_src[p + 2];
        int s3i = csr_src[p + 3];
        __half2 v0 = Hs[(size_t)s0i * 64 + lane];
        __half2 v1 = Hs[(size_t)s1i * 64 + lane];
        __half2 v2 = Hs[(size_t)s2i * 64 + lane];
        __half2 v3 = Hs[(size_t)s3i * 64 + lane];
        float2 f0 = __half22float2(v0), f1 = __half22float2(v1);
        float2 f2 = __half22float2(v2), f3 = __half22float2(v3);
        accx += f0.x; accy += f0.y;
        accx += f1.x; accy += f1.y;
        accx += f2.x; accy += f2.y;
        accx += f3.x; accy += f3.y;
    }
    for (; p < p1; ++p) {
        int s = csr_src[p];
        float2 f = __half22float2(Hs[(size_t)s * 64 + lane]);
        accx += f.x; accy += f.y;
    }

    float di = dis[node];
    float2 bb2 = *(const float2*)(b + 2 * lane);
    float ox = fmaf(accx, di, bb2.x);
    float oy = fmaf(accy, di, bb2.y);
    if (F16OUT) {
        ox = fmaxf(ox, 0.f);                 // relu folded in (next GEMM input)
        oy = fmaxf(oy, 0.f);
        ((__half2*)outv)[(size_t)node * 64 + lane] = __floats2half2_rn(ox, oy);
    } else {
        float2 o; o.x = ox; o.y = oy;
        ((float2*)((float*)outv + (size_t)node * D))[lane] = o;
    }
}

// ---------------- launch ----------------

extern "C" void kernel_launch(void* const* d_in, const int* in_sizes, int n_in,
                              void* d_out, int out_size, void* d_ws, size_t ws_size,
                              hipStream_t stream) {
    const float* x  = (const float*)d_in[0];
    const int*   ei = (const int*)d_in[1];
    const float* W1 = (const float*)d_in[2];
    const float* b1 = (const float*)d_in[3];
    const float* W2 = (const float*)d_in[4];
    const float* b2 = (const float*)d_in[5];
    const float* W3 = (const float*)d_in[6];
    const float* b3 = (const float*)d_in[7];
    float* out = (float*)d_out;

    int n = in_sizes[0] / D;
    int E = in_sizes[1] / 2;
    const int* src = ei;
    const int* dst = ei + E;
    int K = (n + NPB - 1) >> 8;     // buckets

    char* ws = (char*)d_ws;
    half_t* hbuf     = (half_t*)ws; ws += (size_t)n * D * sizeof(half_t);  // H' fp16 (25.6 MB)
    half_t* outh     = (half_t*)ws; ws += (size_t)n * D * sizeof(half_t);  // relu'd out fp16 (25.6 MB)
    float* dis       = (float*)ws;  ws += (size_t)n * sizeof(float);
    int* row_ptr     = (int*)ws;    ws += (size_t)(n + 1) * sizeof(int);
    int* csr_src     = (int*)ws;    ws += (size_t)E * sizeof(int);
    int* bucket_cnt  = (int*)ws;    ws += KMAX * sizeof(int);
    int* bucket_ptr  = (int*)ws;    ws += (KMAX + 1) * sizeof(int);
    int* bucket_cur  = (int*)ws;    ws += KMAX * sizeof(int);
    half_t* Wf1      = (half_t*)ws; ws += 128 * 128 * sizeof(half_t);
    half_t* Wf2      = (half_t*)ws; ws += 128 * 128 * sizeof(half_t);
    half_t* Wf3      = (half_t*)ws; ws += 128 * 128 * sizeof(half_t);
    int2* bdata      = (int2*)hbuf;   // aliases hbuf (12.8 MB); dead before GEMM1 writes it

    int gC = (E + CHUNK - 1) / CHUNK; // 391
    int gM = (n + 63) / 64;           // 1563
    int gA = (n + 3) / 4;             // 25000

    // W pre-pack (fp16 frag order), then CSR build.
    pack_w_kernel<<<32, 256, 0, stream>>>(W1, Wf1);
    pack_w_kernel<<<32, 256, 0, stream>>>(W2, Wf2);
    pack_w_kernel<<<32, 256, 0, stream>>>(W3, Wf3);

    zero_int<<<2, 256, 0, stream>>>(bucket_cnt, KMAX);
    bucket_hist_kernel<<<gC, 256, 0, stream>>>(dst, bucket_cnt, E);
    bucket_scan_kernel<<<1, KMAX, 0, stream>>>(bucket_cnt, bucket_ptr, bucket_cur, K, E);
    bucket_scatter_kernel<<<gC, 256, 0, stream>>>(src, dst, bucket_cur, bdata, E);
    csr_count_scan_kernel<<<K, 256, 0, stream>>>(bdata, bucket_ptr, row_ptr, dis, n, E, K);
    csr_fill_kernel<<<K, 256, 0, stream>>>(bdata, bucket_ptr, row_ptr, csr_src, n);

    // Layer 1: H' = fp16(dis*(x@W1)) ; out1 = relu(agg+b1) fp16
    gemm_mfma_f32in<<<gM, 256, 0, stream>>>(x, Wf1, dis, hbuf, n);
    aggregate_kernel<true><<<gA, 256, 0, stream>>>((const __half2*)hbuf, row_ptr, csr_src, dis, b1, outh, n);
    // Layer 2: H' = fp16(dis*(out1@W2)) ; out2 = relu(agg+b2) fp16
    gemm_mfma_f16in<<<gM, 256, 0, stream>>>(outh, Wf2, dis, hbuf, n);
    aggregate_kernel<true><<<gA, 256, 0, stream>>>((const __half2*)hbuf, row_ptr, csr_src, dis, b2, outh, n);
    // Layer 3: H' = fp16(dis*(out2@W3)) ; out = agg+b3 fp32
    gemm_mfma_f16in<<<gM, 256, 0, stream>>>(outh, Wf3, dis, hbuf, n);
    aggregate_kernel<false><<<gA, 256, 0, stream>>>((const __half2*)hbuf, row_ptr, csr_src, dis, b3, out, n);
}